// Round 11
// baseline (706.166 us; speedup 1.0000x reference)
//
#include <hip/hip_runtime.h>
#include <hip/hip_cooperative_groups.h>
#include <cstddef>

namespace cg = cooperative_groups;

// ---------------------------------------------------------------------------
// GCN forward, fully fused: ONE cooperative persistent kernel.
// phases: cvt(feat,W) | gemm0 | agg0 | gemm1 | agg1 | gemm2 | agg64
// separated by grid.sync(). Phase bodies = R10-proven code (4x16 agg w/
// unroll-2; MFMA gemm with NT=4 half-tiles to keep VGPR<=128 for 4 blk/CU).
// Purpose: eliminate all kernel boundaries AND surface the whole pipeline as
// the top profiled dispatch (R5-R10 could not see past harness fills).
// ---------------------------------------------------------------------------

typedef __attribute__((ext_vector_type(8))) short bf16x8;
typedef __attribute__((ext_vector_type(4))) float floatx4;
typedef __attribute__((ext_vector_type(4))) unsigned int uintx4;
typedef __attribute__((ext_vector_type(2))) unsigned int uintx2;

static __device__ __forceinline__ unsigned int f2bf(float f) {
    union { float f; unsigned int u; } v; v.f = f;
    unsigned int u = v.u;
    u += 0x7fffu + ((u >> 16) & 1u);
    return u >> 16;
}
static __device__ __forceinline__ float bf_lo(unsigned int p) {
    union { unsigned int u; float f; } v; v.u = p << 16; return v.f;
}
static __device__ __forceinline__ float bf_hi(unsigned int p) {
    union { unsigned int u; float f; } v; v.u = p & 0xffff0000u; return v.f;
}

// ---- gemm phase: C[M,NCOLS] = A(bf16) @ W, half-tiles of 16 rows x 64 cols -
template <int NCOLS>
static __device__ __forceinline__ void gemm_phase(const unsigned int* __restrict__ A,
                                                  const unsigned int* __restrict__ Wt,
                                                  unsigned int* __restrict__ C,
                                                  int M, int gwave, int nWaves) {
    const int lane = threadIdx.x & 63;
    const int quad = lane >> 4;
    const int mcol = lane & 15;
    constexpr int HALVES = NCOLS / 64;           // 2 for 128, 1 for 64
    const int rowTiles = (M + 15) >> 4;
    const int totalTiles = rowTiles * HALVES;
    const int rowStride = NCOLS >> 1;            // uints per C row

    for (int t = gwave; t < totalTiles; t += nWaves) {
        const int rowTile = (HALVES == 2) ? (t >> 1) : t;
        const int half    = (HALVES == 2) ? (t & 1) : 0;
        const int row0 = rowTile * 16;
        int aidx = row0 + mcol; if (aidx >= M) aidx = M - 1;
        const unsigned int* arow = A + (size_t)aidx * 64 + quad * 4;
        const unsigned int* WtH  = Wt + (size_t)half * 64 * 64;

        floatx4 acc[4];
        #pragma unroll
        for (int tt = 0; tt < 4; ++tt) acc[tt] = (floatx4){0.f, 0.f, 0.f, 0.f};

        #pragma unroll
        for (int k0 = 0; k0 < 128; k0 += 32) {
            uintx4 ap = *(const uintx4*)(arow + k0 / 2);
            bf16x8 a = __builtin_bit_cast(bf16x8, ap);
            const int koff = (k0 + quad * 8) >> 1;
            #pragma unroll
            for (int tt = 0; tt < 4; ++tt) {
                const unsigned int* brow = WtH + (size_t)(tt * 16 + mcol) * 64 + koff;
                uintx4 bp = *(const uintx4*)brow;
                bf16x8 b = __builtin_bit_cast(bf16x8, bp);
                acc[tt] = __builtin_amdgcn_mfma_f32_16x16x32_bf16(a, b, acc[tt], 0, 0, 0);
            }
        }
        // C/D layout: col = lane&15, row = quad*4 + reg  [m89/m91]
        #pragma unroll
        for (int tt = 0; tt < 4; ++tt) {
            #pragma unroll
            for (int r = 0; r < 4; ++r) {
                unsigned int mybf = f2bf(acc[tt][r]);
                unsigned int pair = __shfl_xor(mybf, 1, 64);
                int orow = row0 + quad * 4 + r;
                if (orow < M && (mcol & 1) == 0) {
                    unsigned int packed = (pair << 16) | mybf;
                    C[(size_t)orow * rowStride + half * 32 + tt * 8 + (mcol >> 1)] = packed;
                }
            }
        }
    }
}

// ---- agg phase, D=128: R10 body (4x16 layout, unroll-2), grid-stride -------
static __device__ __forceinline__ void agg128_phase(const unsigned int* __restrict__ xw,
                                                    const int* __restrict__ ptr,
                                                    const int* __restrict__ col,
                                                    unsigned int* __restrict__ out,
                                                    int N) {
    const int lane = threadIdx.x & 63;
    const int wv = threadIdx.x >> 6;
    const int g  = lane >> 4;
    const int sl = lane & 15;
    const unsigned int* base = xw + sl * 4;

    for (int nb = blockIdx.x; nb * 4 < N; nb += gridDim.x) {
        const int node = nb * 4 + wv;
        if (node < N) {
            const int s = ptr[node];
            const int e = ptr[node + 1];
            float accA[8] = {}, accB[8] = {};
            int i = s + g;
            for (; i + 4 < e; i += 8) {
                uintx4 v0 = *(const uintx4*)(base + (size_t)col[i] * 64);
                uintx4 v1 = *(const uintx4*)(base + (size_t)col[i + 4] * 64);
                accA[0] += bf_lo(v0.x); accA[1] += bf_hi(v0.x);
                accA[2] += bf_lo(v0.y); accA[3] += bf_hi(v0.y);
                accA[4] += bf_lo(v0.z); accA[5] += bf_hi(v0.z);
                accA[6] += bf_lo(v0.w); accA[7] += bf_hi(v0.w);
                accB[0] += bf_lo(v1.x); accB[1] += bf_hi(v1.x);
                accB[2] += bf_lo(v1.y); accB[3] += bf_hi(v1.y);
                accB[4] += bf_lo(v1.z); accB[5] += bf_hi(v1.z);
                accB[6] += bf_lo(v1.w); accB[7] += bf_hi(v1.w);
            }
            if (i < e) {
                uintx4 v0 = *(const uintx4*)(base + (size_t)col[i] * 64);
                accA[0] += bf_lo(v0.x); accA[1] += bf_hi(v0.x);
                accA[2] += bf_lo(v0.y); accA[3] += bf_hi(v0.y);
                accA[4] += bf_lo(v0.z); accA[5] += bf_hi(v0.z);
                accA[6] += bf_lo(v0.w); accA[7] += bf_hi(v0.w);
            }
            float acc[8];
            #pragma unroll
            for (int j = 0; j < 8; ++j) acc[j] = accA[j] + accB[j];
            #pragma unroll
            for (int j = 0; j < 8; ++j) {
                acc[j] += __shfl_xor(acc[j], 16, 64);
                acc[j] += __shfl_xor(acc[j], 32, 64);
            }
            float s1 = 0.f, s2 = 0.f;
            #pragma unroll
            for (int j = 0; j < 8; ++j) { s1 += acc[j]; s2 += acc[j] * acc[j]; }
            #pragma unroll
            for (int m = 8; m >= 1; m >>= 1) {
                s1 += __shfl_xor(s1, m, 64);
                s2 += __shfl_xor(s2, m, 64);
            }
            const float mean = s1 * (1.0f / 128.0f);
            const float var  = s2 * (1.0f / 128.0f) - mean * mean;
            const float inv  = rsqrtf(var + 1e-5f);
            if (g == 0) {
                float o[8];
                #pragma unroll
                for (int j = 0; j < 8; ++j)
                    o[j] = fmaxf((acc[j] - mean) * inv, 0.f);
                uintx4 p;
                p.x = (f2bf(o[1]) << 16) | f2bf(o[0]);
                p.y = (f2bf(o[3]) << 16) | f2bf(o[2]);
                p.z = (f2bf(o[5]) << 16) | f2bf(o[4]);
                p.w = (f2bf(o[7]) << 16) | f2bf(o[6]);
                *(uintx4*)(out + (size_t)node * 64 + sl * 4) = p;
            }
        }
    }
}

// ---- agg phase, D=64, fp32 out, no ReLU ------------------------------------
static __device__ __forceinline__ void agg64_phase(const unsigned int* __restrict__ xw,
                                                   const int* __restrict__ ptr,
                                                   const int* __restrict__ col,
                                                   float* __restrict__ out, int N) {
    const int lane = threadIdx.x & 63;
    const int wv = threadIdx.x >> 6;
    const int g  = lane >> 4;
    const int sl = lane & 15;
    const unsigned int* base = xw + sl * 2;

    for (int nb = blockIdx.x; nb * 4 < N; nb += gridDim.x) {
        const int node = nb * 4 + wv;
        if (node < N) {
            const int s = ptr[node];
            const int e = ptr[node + 1];
            float accA[4] = {}, accB[4] = {};
            int i = s + g;
            for (; i + 4 < e; i += 8) {
                uintx2 v0 = *(const uintx2*)(base + (size_t)col[i] * 32);
                uintx2 v1 = *(const uintx2*)(base + (size_t)col[i + 4] * 32);
                accA[0] += bf_lo(v0.x); accA[1] += bf_hi(v0.x);
                accA[2] += bf_lo(v0.y); accA[3] += bf_hi(v0.y);
                accB[0] += bf_lo(v1.x); accB[1] += bf_hi(v1.x);
                accB[2] += bf_lo(v1.y); accB[3] += bf_hi(v1.y);
            }
            if (i < e) {
                uintx2 v0 = *(const uintx2*)(base + (size_t)col[i] * 32);
                accA[0] += bf_lo(v0.x); accA[1] += bf_hi(v0.x);
                accA[2] += bf_lo(v0.y); accA[3] += bf_hi(v0.y);
            }
            float acc[4];
            #pragma unroll
            for (int j = 0; j < 4; ++j) acc[j] = accA[j] + accB[j];
            #pragma unroll
            for (int j = 0; j < 4; ++j) {
                acc[j] += __shfl_xor(acc[j], 16, 64);
                acc[j] += __shfl_xor(acc[j], 32, 64);
            }
            float s1 = 0.f, s2 = 0.f;
            #pragma unroll
            for (int j = 0; j < 4; ++j) { s1 += acc[j]; s2 += acc[j] * acc[j]; }
            #pragma unroll
            for (int m = 8; m >= 1; m >>= 1) {
                s1 += __shfl_xor(s1, m, 64);
                s2 += __shfl_xor(s2, m, 64);
            }
            const float mean = s1 * (1.0f / 64.0f);
            const float var  = s2 * (1.0f / 64.0f) - mean * mean;
            const float inv  = rsqrtf(var + 1e-5f);
            if (g == 0) {
                float4 o;
                o.x = (acc[0] - mean) * inv;
                o.y = (acc[1] - mean) * inv;
                o.z = (acc[2] - mean) * inv;
                o.w = (acc[3] - mean) * inv;
                *(float4*)(out + (size_t)node * 64 + sl * 4) = o;
            }
        }
    }
}

// ---- the one kernel --------------------------------------------------------
__global__ __launch_bounds__(256, 4) void gcn_fused(
    const float* __restrict__ feat, const float* __restrict__ W0,
    const float* __restrict__ W1, const float* __restrict__ W2,
    const int* __restrict__ ptr, const int* __restrict__ col,
    unsigned int* __restrict__ xwp, unsigned int* __restrict__ hb,
    unsigned int* __restrict__ fb, unsigned int* __restrict__ WtP,
    float* __restrict__ out, int N)
{
    cg::grid_group grid = cg::this_grid();
    const int gtid = blockIdx.x * 256 + threadIdx.x;
    const int nThreads = gridDim.x * 256;
    const int gwave = blockIdx.x * 4 + (threadIdx.x >> 6);
    const int nWaves = gridDim.x * 4;

    // phase A: convert feat -> packed bf16, W -> transposed packed bf16
    {
        const int n8 = N * 16;
        for (int i = gtid; i < n8; i += nThreads) {
            float4 a = ((const float4*)feat)[i * 2];
            float4 b = ((const float4*)feat)[i * 2 + 1];
            uintx4 p;
            p.x = (f2bf(a.y) << 16) | f2bf(a.x);
            p.y = (f2bf(a.w) << 16) | f2bf(a.z);
            p.z = (f2bf(b.y) << 16) | f2bf(b.x);
            p.w = (f2bf(b.w) << 16) | f2bf(b.z);
            ((uintx4*)fb)[i] = p;
        }
        #pragma unroll
        for (int m = 0; m < 3; ++m) {
            const float* W = (m == 0) ? W0 : (m == 1) ? W1 : W2;
            const int ncols = (m == 2) ? 64 : 128;
            unsigned int* dst = WtP + m * 128 * 64;
            const int total = ncols * 64;
            for (int idx = gtid; idx < total; idx += nThreads) {
                int kk = idx / ncols;
                int n  = idx - kk * ncols;
                unsigned int lo = f2bf(W[(size_t)(2 * kk) * ncols + n]);
                unsigned int hi = f2bf(W[(size_t)(2 * kk + 1) * ncols + n]);
                dst[(size_t)n * 64 + kk] = (hi << 16) | lo;
            }
        }
    }
    grid.sync();

    // layer 0
    gemm_phase<128>(fb, WtP, xwp, N, gwave, nWaves);
    grid.sync();
    agg128_phase(xwp, ptr, col, hb, N);
    grid.sync();
    // layer 1
    gemm_phase<128>(hb, WtP + 128 * 64, xwp, N, gwave, nWaves);
    grid.sync();
    agg128_phase(xwp, ptr, col, hb, N);
    grid.sync();
    // layer 2
    gemm_phase<64>(hb, WtP + 2 * 128 * 64, xwp, N, gwave, nWaves);
    grid.sync();
    agg64_phase(xwp, ptr, col, out, N);
}

extern "C" void kernel_launch(void* const* d_in, const int* in_sizes, int n_in,
                              void* d_out, int out_size, void* d_ws, size_t ws_size,
                              hipStream_t stream) {
    const float* feat = (const float*)d_in[0];   // [N,128]
    const float* W0   = (const float*)d_in[1];   // [128,128]
    const float* W1   = (const float*)d_in[2];   // [128,128]
    const float* W2   = (const float*)d_in[3];   // [128,64]
    const int*   ptr  = (const int*)d_in[4];     // [N+1]
    const int*   col  = (const int*)d_in[5];     // [E]
    // d_in[6] = edge_rows, unused (CSR ptr encodes the same segments)

    int N = in_sizes[4] - 1;                     // 50000

    unsigned int* xwp = (unsigned int*)d_ws;                 // [N,64] uint (bf16x2)
    unsigned int* hb  = xwp + (size_t)N * 64;                // [N,64] uint (bf16x2)
    unsigned int* fb  = hb + (size_t)N * 64;                 // [N,64] uint (bf16 feat)
    unsigned int* WtP = fb + (size_t)N * 64;                 // 3 x [128,64] uint
    float*        out = (float*)d_out;                       // [N,64]

    int maxB = 0;
    if (hipOccupancyMaxActiveBlocksPerMultiprocessor(
            &maxB, reinterpret_cast<const void*>(gcn_fused), 256, 0) != hipSuccess ||
        maxB <= 0)
        maxB = 2;
    if (maxB > 4) maxB = 4;
    dim3 gridDim(maxB * 256), blockDim(256);

    void* args[] = {
        (void*)&feat, (void*)&W0, (void*)&W1, (void*)&W2,
        (void*)&ptr, (void*)&col,
        (void*)&xwp, (void*)&hb, (void*)&fb, (void*)&WtP,
        (void*)&out, (void*)&N
    };
    hipLaunchCooperativeKernel(reinterpret_cast<void*>(gcn_fused),
                               gridDim, blockDim, args, 0, stream);
}

// Round 12
// 223.342 us; speedup vs baseline: 3.1618x; 3.1618x over previous
//
#include <hip/hip_runtime.h>
#include <cstddef>

// ---------------------------------------------------------------------------
// GCN forward: 3 x ( h@W bf16 MFMA -> packed-bf16 xw -> CSR segsum+LN(+ReLU) )
// N=50000, E=800000, D: 128 -> 128 -> 128 -> 64.
// R12 = R10 (best, 227.8us) + (1) agg unroll-4: 4 independent gathers in
// flight per wave (R11's fused-PMC proved aggs are latency-depth-bound, gemms
// ~2us of MFMA); (2) cvt_feat folded into gemm0 (fp32 A path, R5/R6-proven).
// R11 cooperative fusion reverted (1024-block cap destroyed agg parallelism).
// ---------------------------------------------------------------------------

typedef __attribute__((ext_vector_type(8))) short bf16x8;
typedef __attribute__((ext_vector_type(4))) float floatx4;
typedef __attribute__((ext_vector_type(4))) unsigned int uintx4;
typedef __attribute__((ext_vector_type(2))) unsigned int uintx2;

static __device__ __forceinline__ unsigned int f2bf(float f) {
    union { float f; unsigned int u; } v; v.f = f;
    unsigned int u = v.u;
    u += 0x7fffu + ((u >> 16) & 1u);
    return u >> 16;
}
static __device__ __forceinline__ float bf_lo(unsigned int p) {
    union { unsigned int u; float f; } v; v.u = p << 16; return v.f;
}
static __device__ __forceinline__ float bf_hi(unsigned int p) {
    union { unsigned int u; float f; } v; v.u = p & 0xffff0000u; return v.f;
}
static __device__ __forceinline__ void acc8(float* a, uintx4 v) {
    a[0] += bf_lo(v.x); a[1] += bf_hi(v.x);
    a[2] += bf_lo(v.y); a[3] += bf_hi(v.y);
    a[4] += bf_lo(v.z); a[5] += bf_hi(v.z);
    a[6] += bf_lo(v.w); a[7] += bf_hi(v.w);
}
static __device__ __forceinline__ void acc4(float* a, uintx2 v) {
    a[0] += bf_lo(v.x); a[1] += bf_hi(v.x);
    a[2] += bf_lo(v.y); a[3] += bf_hi(v.y);
}

// ---- W[k][n] fp32 -> Wt[n][kk] packed bf16 pairs (uint), 3 matrices --------
__global__ __launch_bounds__(256) void cvt_w(const float* __restrict__ W0,
                                             const float* __restrict__ W1,
                                             const float* __restrict__ W2,
                                             unsigned int* __restrict__ Wt) {
    const int m = blockIdx.x >> 4;
    const int slice = blockIdx.x & 15;
    const float* W = (m == 0) ? W0 : (m == 1) ? W1 : W2;
    const int ncols = (m == 2) ? 64 : 128;
    unsigned int* dst = Wt + m * 128 * 64;
    const int total = ncols * 64;
    for (int idx = slice * 256 + threadIdx.x; idx < total; idx += 16 * 256) {
        int kk = idx / ncols;
        int n  = idx - kk * ncols;
        unsigned int lo = f2bf(W[(size_t)(2 * kk) * ncols + n]);
        unsigned int hi = f2bf(W[(size_t)(2 * kk + 1) * ncols + n]);
        dst[(size_t)n * 64 + kk] = (hi << 16) | lo;
    }
}

// ---- bf16 MFMA GEMM, 1 wave per block (16 rows x NCOLS) --------------------
// A_FP32: layer-0 reads fp32 feat and converts in-register (R5/R6-proven,
// R7 showed it's perf-neutral vs bf16 A). Otherwise reads packed-bf16 A.
template <int NCOLS, bool A_FP32>
__global__ __launch_bounds__(64) void gemm_mfma(const void* __restrict__ Av,
                                                const unsigned int* __restrict__ Wt,
                                                unsigned int* __restrict__ C,
                                                int M) {
    const int lane = threadIdx.x;
    const int row0 = blockIdx.x * 16;
    const int quad = lane >> 4;
    const int mcol = lane & 15;
    int aidx = row0 + mcol; if (aidx >= M) aidx = M - 1;

    constexpr int NT = NCOLS / 16;
    floatx4 acc[NT];
    #pragma unroll
    for (int t = 0; t < NT; ++t) acc[t] = (floatx4){0.f, 0.f, 0.f, 0.f};

    const float*        arowF = (const float*)Av + (size_t)aidx * 128 + quad * 8;
    const unsigned int* arowB = (const unsigned int*)Av + (size_t)aidx * 64 + quad * 4;

    #pragma unroll
    for (int k0 = 0; k0 < 128; k0 += 32) {
        bf16x8 a;
        if constexpr (A_FP32) {
            float4 fa = *(const float4*)(arowF + k0);
            float4 fb = *(const float4*)(arowF + k0 + 4);
            uintx4 ap;
            ap.x = (f2bf(fa.y) << 16) | f2bf(fa.x);
            ap.y = (f2bf(fa.w) << 16) | f2bf(fa.z);
            ap.z = (f2bf(fb.y) << 16) | f2bf(fb.x);
            ap.w = (f2bf(fb.w) << 16) | f2bf(fb.z);
            a = __builtin_bit_cast(bf16x8, ap);
        } else {
            uintx4 ap = *(const uintx4*)(arowB + k0 / 2);
            a = __builtin_bit_cast(bf16x8, ap);
        }

        const int koff = (k0 + quad * 8) >> 1;
        #pragma unroll
        for (int t = 0; t < NT; ++t) {
            const unsigned int* brow = Wt + (size_t)(t * 16 + mcol) * 64 + koff;
            uintx4 bp = *(const uintx4*)brow;
            bf16x8 b = __builtin_bit_cast(bf16x8, bp);
            acc[t] = __builtin_amdgcn_mfma_f32_16x16x32_bf16(a, b, acc[t], 0, 0, 0);
        }
    }

    // C/D layout: col = lane&15, row = quad*4 + reg  [m89/m91]
    const int rowStride = NCOLS >> 1;
    #pragma unroll
    for (int t = 0; t < NT; ++t) {
        #pragma unroll
        for (int r = 0; r < 4; ++r) {
            unsigned int mybf = f2bf(acc[t][r]);
            unsigned int pair = __shfl_xor(mybf, 1, 64);
            int orow = row0 + quad * 4 + r;
            if (orow < M && (mcol & 1) == 0) {
                unsigned int packed = (pair << 16) | mybf;
                C[(size_t)orow * rowStride + t * 8 + (mcol >> 1)] = packed;
            }
        }
    }
}

// ---- fused CSR segsum + LN + ReLU, D=128, packed-bf16 out ------------------
// 4x16 lane layout (g=edge group, sl=sublane owning 8 feats, uintx4/edge)
// with unroll-4: gathers for edges i, i+4, i+8, i+12 all in flight.
// deg=16 (avg) -> exactly one full iteration, empty tail.
__global__ __launch_bounds__(256) void agg_ln128(const unsigned int* __restrict__ xw,
                                                 const int* __restrict__ ptr,
                                                 const int* __restrict__ col,
                                                 unsigned int* __restrict__ out,
                                                 int N) {
    const int node = blockIdx.x * 4 + (threadIdx.x >> 6);
    if (node >= N) return;
    const int lane = threadIdx.x & 63;
    const int g  = lane >> 4;     // 0..3 edge group
    const int sl = lane & 15;     // 0..15 sublane (owns 8 features)
    const int s = ptr[node];
    const int e = ptr[node + 1];

    float accA[8] = {}, accB[8] = {};
    const unsigned int* base = xw + sl * 4;
    int i = s + g;
    for (; i + 12 < e; i += 16) {
        uintx4 v0 = *(const uintx4*)(base + (size_t)col[i]      * 64);
        uintx4 v1 = *(const uintx4*)(base + (size_t)col[i + 4]  * 64);
        uintx4 v2 = *(const uintx4*)(base + (size_t)col[i + 8]  * 64);
        uintx4 v3 = *(const uintx4*)(base + (size_t)col[i + 12] * 64);
        acc8(accA, v0); acc8(accB, v1); acc8(accA, v2); acc8(accB, v3);
    }
    for (; i < e; i += 4) {
        uintx4 v0 = *(const uintx4*)(base + (size_t)col[i] * 64);
        acc8(accA, v0);
    }

    float acc[8];
    #pragma unroll
    for (int j = 0; j < 8; ++j) acc[j] = accA[j] + accB[j];

    // combine the 4 edge groups (lane bits 4,5)
    #pragma unroll
    for (int j = 0; j < 8; ++j) {
        acc[j] += __shfl_xor(acc[j], 16, 64);
        acc[j] += __shfl_xor(acc[j], 32, 64);
    }
    // LN stats over the 16 sublanes (lane bits 0..3)
    float s1 = 0.f, s2 = 0.f;
    #pragma unroll
    for (int j = 0; j < 8; ++j) { s1 += acc[j]; s2 += acc[j] * acc[j]; }
    #pragma unroll
    for (int m = 8; m >= 1; m >>= 1) {
        s1 += __shfl_xor(s1, m, 64);
        s2 += __shfl_xor(s2, m, 64);
    }
    const float mean = s1 * (1.0f / 128.0f);
    const float var  = s2 * (1.0f / 128.0f) - mean * mean;
    const float inv  = rsqrtf(var + 1e-5f);

    if (g == 0) {
        float o[8];
        #pragma unroll
        for (int j = 0; j < 8; ++j)
            o[j] = fmaxf((acc[j] - mean) * inv, 0.f);
        uintx4 p;
        p.x = (f2bf(o[1]) << 16) | f2bf(o[0]);
        p.y = (f2bf(o[3]) << 16) | f2bf(o[2]);
        p.z = (f2bf(o[5]) << 16) | f2bf(o[4]);
        p.w = (f2bf(o[7]) << 16) | f2bf(o[6]);
        *(uintx4*)(out + (size_t)node * 64 + sl * 4) = p;
    }
}

// ---- fused CSR segsum + LN, D=64, fp32 out, no ReLU (final layer) ----------
__global__ __launch_bounds__(256) void agg_ln64(const unsigned int* __restrict__ xw,
                                                const int* __restrict__ ptr,
                                                const int* __restrict__ col,
                                                float* __restrict__ out, int N) {
    const int node = blockIdx.x * 4 + (threadIdx.x >> 6);
    if (node >= N) return;
    const int lane = threadIdx.x & 63;
    const int g  = lane >> 4;     // 0..3 edge group
    const int sl = lane & 15;     // 0..15 sublane (owns 4 features)
    const int s = ptr[node];
    const int e = ptr[node + 1];

    float accA[4] = {}, accB[4] = {};
    const unsigned int* base = xw + sl * 2;
    int i = s + g;
    for (; i + 12 < e; i += 16) {
        uintx2 v0 = *(const uintx2*)(base + (size_t)col[i]      * 32);
        uintx2 v1 = *(const uintx2*)(base + (size_t)col[i + 4]  * 32);
        uintx2 v2 = *(const uintx2*)(base + (size_t)col[i + 8]  * 32);
        uintx2 v3 = *(const uintx2*)(base + (size_t)col[i + 12] * 32);
        acc4(accA, v0); acc4(accB, v1); acc4(accA, v2); acc4(accB, v3);
    }
    for (; i < e; i += 4) {
        uintx2 v0 = *(const uintx2*)(base + (size_t)col[i] * 32);
        acc4(accA, v0);
    }

    float acc[4];
    #pragma unroll
    for (int j = 0; j < 4; ++j) acc[j] = accA[j] + accB[j];

    #pragma unroll
    for (int j = 0; j < 4; ++j) {
        acc[j] += __shfl_xor(acc[j], 16, 64);
        acc[j] += __shfl_xor(acc[j], 32, 64);
    }
    float s1 = 0.f, s2 = 0.f;
    #pragma unroll
    for (int j = 0; j < 4; ++j) { s1 += acc[j]; s2 += acc[j] * acc[j]; }
    #pragma unroll
    for (int m = 8; m >= 1; m >>= 1) {
        s1 += __shfl_xor(s1, m, 64);
        s2 += __shfl_xor(s2, m, 64);
    }
    const float mean = s1 * (1.0f / 64.0f);
    const float var  = s2 * (1.0f / 64.0f) - mean * mean;
    const float inv  = rsqrtf(var + 1e-5f);

    if (g == 0) {
        float4 o;
        o.x = (acc[0] - mean) * inv;
        o.y = (acc[1] - mean) * inv;
        o.z = (acc[2] - mean) * inv;
        o.w = (acc[3] - mean) * inv;
        *(float4*)(out + (size_t)node * 64 + sl * 4) = o;
    }
}

extern "C" void kernel_launch(void* const* d_in, const int* in_sizes, int n_in,
                              void* d_out, int out_size, void* d_ws, size_t ws_size,
                              hipStream_t stream) {
    const float* feat = (const float*)d_in[0];   // [N,128]
    const float* W0   = (const float*)d_in[1];   // [128,128]
    const float* W1   = (const float*)d_in[2];   // [128,128]
    const float* W2   = (const float*)d_in[3];   // [128,64]
    const int*   ptr  = (const int*)d_in[4];     // [N+1]
    const int*   col  = (const int*)d_in[5];     // [E]
    // d_in[6] = edge_rows, unused (CSR ptr encodes the same segments)

    const int N = in_sizes[4] - 1;               // 50000

    unsigned int* xwp = (unsigned int*)d_ws;                 // [N,64] uint (bf16x2)
    unsigned int* hb  = xwp + (size_t)N * 64;                // [N,64] uint (bf16x2)
    unsigned int* WtP = hb + (size_t)N * 64;                 // 3 x [128,64] uint
    float*        out = (float*)d_out;                       // [N,64]

    const int gemmBlocks = (N + 15) / 16;        // 3125 (1 wave each)
    const int nodeBlocks = (N + 3) / 4;          // 12500

    cvt_w<<<48, 256, 0, stream>>>(W0, W1, W2, WtP);

    // Layer 0 (fp32 feat A-path, in-register convert)
    gemm_mfma<128, true><<<gemmBlocks, 64, 0, stream>>>(feat, WtP, xwp, N);
    agg_ln128<<<nodeBlocks, 256, 0, stream>>>(xwp, ptr, col, hb, N);
    // Layer 1
    gemm_mfma<128, false><<<gemmBlocks, 64, 0, stream>>>(hb, WtP + 128 * 64, xwp, N);
    agg_ln128<<<nodeBlocks, 256, 0, stream>>>(xwp, ptr, col, hb, N);
    // Layer 2 (D_out=64, no ReLU, fp32 out)
    gemm_mfma<64, false><<<gemmBlocks, 64, 0, stream>>>(hb, WtP + 2 * 128 * 64, xwp, N);
    agg_ln64<<<nodeBlocks, 256, 0, stream>>>(xwp, ptr, col, out, N);
}

// Round 13
// 201.810 us; speedup vs baseline: 3.4992x; 1.1067x over previous
//
#include <hip/hip_runtime.h>
#include <cstddef>

// ---------------------------------------------------------------------------
// GCN forward: 3 x ( h@W bf16 MFMA -> packed-bf16 xw -> CSR segsum+LN(+ReLU) )
// N=50000, E=800000, D: 128 -> 128 -> 128 -> 64.
// R13 = R12 + MFMA-FRAGMENT-ORDERED operands:
//  - WtF: B fragments stored lane-contiguous (B load was 16-way sector-split:
//    lanes strided 256B; R5 evidence says gemms ~40-50us scatter-bound).
//  - agg128 writes h in A-fragment order (address permutation only) so
//    gemm1/2 A loads are lane-contiguous too. N = 3125*16 exactly.
//  - gemm0 keeps fp32-feat A path; xw stays row-major for the agg gather.
// ---------------------------------------------------------------------------

typedef __attribute__((ext_vector_type(8))) short bf16x8;
typedef __attribute__((ext_vector_type(4))) float floatx4;
typedef __attribute__((ext_vector_type(4))) unsigned int uintx4;
typedef __attribute__((ext_vector_type(2))) unsigned int uintx2;

static __device__ __forceinline__ unsigned int f2bf(float f) {
    union { float f; unsigned int u; } v; v.f = f;
    unsigned int u = v.u;
    u += 0x7fffu + ((u >> 16) & 1u);
    return u >> 16;
}
static __device__ __forceinline__ float bf_lo(unsigned int p) {
    union { unsigned int u; float f; } v; v.u = p << 16; return v.f;
}
static __device__ __forceinline__ float bf_hi(unsigned int p) {
    union { unsigned int u; float f; } v; v.u = p & 0xffff0000u; return v.f;
}
static __device__ __forceinline__ void acc8(float* a, uintx4 v) {
    a[0] += bf_lo(v.x); a[1] += bf_hi(v.x);
    a[2] += bf_lo(v.y); a[3] += bf_hi(v.y);
    a[4] += bf_lo(v.z); a[5] += bf_hi(v.z);
    a[6] += bf_lo(v.w); a[7] += bf_hi(v.w);
}
static __device__ __forceinline__ void acc4(float* a, uintx2 v) {
    a[0] += bf_lo(v.x); a[1] += bf_hi(v.x);
    a[2] += bf_lo(v.y); a[3] += bf_hi(v.y);
}

// ---- W[k][n] fp32 -> FRAGMENT-ORDERED WtF, 3 matrices ----------------------
// Layout: uint idx = t*1024 + s*256 + lane*4 + j  (t = 16-col tile, s = k0/32,
// lane = quad*16+mcol). Holds packed bf16 pair W[k][n],W[k+1][n] with
// n = t*16+mcol, k = s*32+quad*8+2j. B-load in gemm = lane-contiguous uintx4.
__global__ __launch_bounds__(256) void cvt_w(const float* __restrict__ W0,
                                             const float* __restrict__ W1,
                                             const float* __restrict__ W2,
                                             unsigned int* __restrict__ WtF) {
    const int m = blockIdx.x >> 4;
    const int slice = blockIdx.x & 15;
    const float* W = (m == 0) ? W0 : (m == 1) ? W1 : W2;
    const int ncols = (m == 2) ? 64 : 128;
    unsigned int* dst = WtF + m * 128 * 64;
    const int total = ncols * 64;                  // uints
    for (int idx = slice * 256 + threadIdx.x; idx < total; idx += 16 * 256) {
        const int j    = idx & 3;
        const int lane = (idx >> 2) & 63;
        const int s    = (idx >> 8) & 3;
        const int t    = idx >> 10;
        const int mcol = lane & 15;
        const int quad = lane >> 4;
        const int n = t * 16 + mcol;
        const int k = s * 32 + quad * 8 + 2 * j;
        unsigned int lo = f2bf(W[(size_t)k * ncols + n]);
        unsigned int hi = f2bf(W[(size_t)(k + 1) * ncols + n]);
        dst[idx] = (hi << 16) | lo;
    }
}

// ---- bf16 MFMA GEMM, 1 wave per block (16 rows x NCOLS) --------------------
// B from fragment-ordered WtF (coalesced). A: fp32 row-major (layer 0) or
// fragment-ordered bf16 (layers 1,2; written by agg128). C row-major packed.
template <int NCOLS, bool A_FP32>
__global__ __launch_bounds__(64) void gemm_mfma(const void* __restrict__ Av,
                                                const unsigned int* __restrict__ Wt,
                                                unsigned int* __restrict__ C,
                                                int M) {
    const int lane = threadIdx.x;
    const int row0 = blockIdx.x * 16;
    const int quad = lane >> 4;
    const int mcol = lane & 15;

    constexpr int NT = NCOLS / 16;
    floatx4 acc[NT];
    #pragma unroll
    for (int t = 0; t < NT; ++t) acc[t] = (floatx4){0.f, 0.f, 0.f, 0.f};

    int aidx = row0 + mcol; if (aidx >= M) aidx = M - 1;
    const float*        arowF = (const float*)Av + (size_t)aidx * 128 + quad * 8;
    const unsigned int* afrag = (const unsigned int*)Av + (size_t)blockIdx.x * 1024 + lane * 4;
    const unsigned int* bbase = Wt + lane * 4;

    #pragma unroll
    for (int s = 0; s < 4; ++s) {
        bf16x8 a;
        if constexpr (A_FP32) {
            float4 fa = *(const float4*)(arowF + s * 32);
            float4 fb = *(const float4*)(arowF + s * 32 + 4);
            uintx4 ap;
            ap.x = (f2bf(fa.y) << 16) | f2bf(fa.x);
            ap.y = (f2bf(fa.w) << 16) | f2bf(fa.z);
            ap.z = (f2bf(fb.y) << 16) | f2bf(fb.x);
            ap.w = (f2bf(fb.w) << 16) | f2bf(fb.z);
            a = __builtin_bit_cast(bf16x8, ap);
        } else {
            uintx4 ap = *(const uintx4*)(afrag + s * 256);
            a = __builtin_bit_cast(bf16x8, ap);
        }
        #pragma unroll
        for (int t = 0; t < NT; ++t) {
            uintx4 bp = *(const uintx4*)(bbase + t * 1024 + s * 256);
            bf16x8 b = __builtin_bit_cast(bf16x8, bp);
            acc[t] = __builtin_amdgcn_mfma_f32_16x16x32_bf16(a, b, acc[t], 0, 0, 0);
        }
    }

    // C/D layout: col = lane&15, row = quad*4 + reg  [m89/m91]; row-major out.
    const int rowStride = NCOLS >> 1;
    #pragma unroll
    for (int t = 0; t < NT; ++t) {
        #pragma unroll
        for (int r = 0; r < 4; ++r) {
            unsigned int mybf = f2bf(acc[t][r]);
            unsigned int pair = __shfl_xor(mybf, 1, 64);
            int orow = row0 + quad * 4 + r;
            if (orow < M && (mcol & 1) == 0) {
                unsigned int packed = (pair << 16) | mybf;
                C[(size_t)orow * rowStride + t * 8 + (mcol >> 1)] = packed;
            }
        }
    }
}

// ---- fused CSR segsum + LN + ReLU, D=128 -----------------------------------
// R12 body (4x16 layout, unroll-4 gather). OUTPUT in A-fragment order for the
// next gemm: (node=tile*16+m, sublane sl owning feats sl*8..sl*8+7) stores at
// tile*1024 + (sl>>2)*256 + (sl&3)*64 + m*4. Block's 4 consecutive nodes
// complete each 64B sector.
__global__ __launch_bounds__(256) void agg_ln128(const unsigned int* __restrict__ xw,
                                                 const int* __restrict__ ptr,
                                                 const int* __restrict__ col,
                                                 unsigned int* __restrict__ out,
                                                 int N) {
    const int node = blockIdx.x * 4 + (threadIdx.x >> 6);
    if (node >= N) return;
    const int lane = threadIdx.x & 63;
    const int g  = lane >> 4;     // 0..3 edge group
    const int sl = lane & 15;     // 0..15 sublane (owns 8 features)
    const int s = ptr[node];
    const int e = ptr[node + 1];

    float accA[8] = {}, accB[8] = {};
    const unsigned int* base = xw + sl * 4;
    int i = s + g;
    for (; i + 12 < e; i += 16) {
        uintx4 v0 = *(const uintx4*)(base + (size_t)col[i]      * 64);
        uintx4 v1 = *(const uintx4*)(base + (size_t)col[i + 4]  * 64);
        uintx4 v2 = *(const uintx4*)(base + (size_t)col[i + 8]  * 64);
        uintx4 v3 = *(const uintx4*)(base + (size_t)col[i + 12] * 64);
        acc8(accA, v0); acc8(accB, v1); acc8(accA, v2); acc8(accB, v3);
    }
    for (; i < e; i += 4) {
        uintx4 v0 = *(const uintx4*)(base + (size_t)col[i] * 64);
        acc8(accA, v0);
    }

    float acc[8];
    #pragma unroll
    for (int j = 0; j < 8; ++j) acc[j] = accA[j] + accB[j];

    #pragma unroll
    for (int j = 0; j < 8; ++j) {
        acc[j] += __shfl_xor(acc[j], 16, 64);
        acc[j] += __shfl_xor(acc[j], 32, 64);
    }
    float s1 = 0.f, s2 = 0.f;
    #pragma unroll
    for (int j = 0; j < 8; ++j) { s1 += acc[j]; s2 += acc[j] * acc[j]; }
    #pragma unroll
    for (int m = 8; m >= 1; m >>= 1) {
        s1 += __shfl_xor(s1, m, 64);
        s2 += __shfl_xor(s2, m, 64);
    }
    const float mean = s1 * (1.0f / 128.0f);
    const float var  = s2 * (1.0f / 128.0f) - mean * mean;
    const float inv  = rsqrtf(var + 1e-5f);

    if (g == 0) {
        float o[8];
        #pragma unroll
        for (int j = 0; j < 8; ++j)
            o[j] = fmaxf((acc[j] - mean) * inv, 0.f);
        uintx4 p;
        p.x = (f2bf(o[1]) << 16) | f2bf(o[0]);
        p.y = (f2bf(o[3]) << 16) | f2bf(o[2]);
        p.z = (f2bf(o[5]) << 16) | f2bf(o[4]);
        p.w = (f2bf(o[7]) << 16) | f2bf(o[6]);
        const int tile = node >> 4, m = node & 15;
        *(uintx4*)(out + (size_t)tile * 1024 + (sl >> 2) * 256 + (sl & 3) * 64 + m * 4) = p;
    }
}

// ---- fused CSR segsum + LN, D=64, fp32 out, no ReLU (final layer) ----------
__global__ __launch_bounds__(256) void agg_ln64(const unsigned int* __restrict__ xw,
                                                const int* __restrict__ ptr,
                                                const int* __restrict__ col,
                                                float* __restrict__ out, int N) {
    const int node = blockIdx.x * 4 + (threadIdx.x >> 6);
    if (node >= N) return;
    const int lane = threadIdx.x & 63;
    const int g  = lane >> 4;     // 0..3 edge group
    const int sl = lane & 15;     // 0..15 sublane (owns 4 features)
    const int s = ptr[node];
    const int e = ptr[node + 1];

    float accA[4] = {}, accB[4] = {};
    const unsigned int* base = xw + sl * 2;
    int i = s + g;
    for (; i + 12 < e; i += 16) {
        uintx2 v0 = *(const uintx2*)(base + (size_t)col[i]      * 32);
        uintx2 v1 = *(const uintx2*)(base + (size_t)col[i + 4]  * 32);
        uintx2 v2 = *(const uintx2*)(base + (size_t)col[i + 8]  * 32);
        uintx2 v3 = *(const uintx2*)(base + (size_t)col[i + 12] * 32);
        acc4(accA, v0); acc4(accB, v1); acc4(accA, v2); acc4(accB, v3);
    }
    for (; i < e; i += 4) {
        uintx2 v0 = *(const uintx2*)(base + (size_t)col[i] * 32);
        acc4(accA, v0);
    }

    float acc[4];
    #pragma unroll
    for (int j = 0; j < 4; ++j) acc[j] = accA[j] + accB[j];

    #pragma unroll
    for (int j = 0; j < 4; ++j) {
        acc[j] += __shfl_xor(acc[j], 16, 64);
        acc[j] += __shfl_xor(acc[j], 32, 64);
    }
    float s1 = 0.f, s2 = 0.f;
    #pragma unroll
    for (int j = 0; j < 4; ++j) { s1 += acc[j]; s2 += acc[j] * acc[j]; }
    #pragma unroll
    for (int m = 8; m >= 1; m >>= 1) {
        s1 += __shfl_xor(s1, m, 64);
        s2 += __shfl_xor(s2, m, 64);
    }
    const float mean = s1 * (1.0f / 64.0f);
    const float var  = s2 * (1.0f / 64.0f) - mean * mean;
    const float inv  = rsqrtf(var + 1e-5f);

    if (g == 0) {
        float4 o;
        o.x = (acc[0] - mean) * inv;
        o.y = (acc[1] - mean) * inv;
        o.z = (acc[2] - mean) * inv;
        o.w = (acc[3] - mean) * inv;
        *(float4*)(out + (size_t)node * 64 + sl * 4) = o;
    }
}

extern "C" void kernel_launch(void* const* d_in, const int* in_sizes, int n_in,
                              void* d_out, int out_size, void* d_ws, size_t ws_size,
                              hipStream_t stream) {
    const float* feat = (const float*)d_in[0];   // [N,128]
    const float* W0   = (const float*)d_in[1];   // [128,128]
    const float* W1   = (const float*)d_in[2];   // [128,128]
    const float* W2   = (const float*)d_in[3];   // [128,64]
    const int*   ptr  = (const int*)d_in[4];     // [N+1]
    const int*   col  = (const int*)d_in[5];     // [E]
    // d_in[6] = edge_rows, unused (CSR ptr encodes the same segments)

    const int N = in_sizes[4] - 1;               // 50000 (= 3125 * 16)

    unsigned int* xwp = (unsigned int*)d_ws;                 // [N,64] uint, row-major
    unsigned int* hb  = xwp + (size_t)N * 64;                // [N,64] uint, A-frag order
    unsigned int* WtP = hb + (size_t)N * 64;                 // 3 x frag-ordered W
    float*        out = (float*)d_out;                       // [N,64]

    const int gemmBlocks = (N + 15) / 16;        // 3125 (1 wave each)
    const int nodeBlocks = (N + 3) / 4;          // 12500

    cvt_w<<<48, 256, 0, stream>>>(W0, W1, W2, WtP);

    // Layer 0 (fp32 feat A-path, in-register convert)
    gemm_mfma<128, true><<<gemmBlocks, 64, 0, stream>>>(feat, WtP, xwp, N);
    agg_ln128<<<nodeBlocks, 256, 0, stream>>>(xwp, ptr, col, hb, N);
    // Layer 1 (A fragment-ordered)
    gemm_mfma<128, false><<<gemmBlocks, 64, 0, stream>>>(hb, WtP + 128 * 64, xwp, N);
    agg_ln128<<<nodeBlocks, 256, 0, stream>>>(xwp, ptr, col, hb, N);
    // Layer 2 (D_out=64, no ReLU, fp32 out)
    gemm_mfma<64, false><<<gemmBlocks, 64, 0, stream>>>(hb, WtP + 2 * 128 * 64, xwp, N);
    agg_ln64<<<nodeBlocks, 256, 0, stream>>>(xwp, ptr, col, out, N);
}